// Round 19
// baseline (275.521 us; speedup 1.0000x reference)
//
#include <hip/hip_runtime.h>
#include <math.h>

#define S_LEN 512
#define D_IN  768
#define H_DIM 50
#define G4    200
#define NCT   13
#define KSTEPS 24        // 768/32
#define FR_KS  6656      // ushorts per K-step: 13 ct x 64 lanes x 8
#define CHROWS 32        // rows per chunk
#define NSLOT  5         // LDS ring slots (133 KB)
#define ROWSTR 208       // floats per LDS row

typedef float   f32x4 __attribute__((ext_vector_type(4)));
typedef short   s16x8 __attribute__((ext_vector_type(8)));
typedef _Float16 f16x2 __attribute__((ext_vector_type(2)));

__device__ ushort g_Wf[KSTEPS * FR_KS];   // [ks][ct][lane][8], RNE bf16

#define LOG2E 1.44269504f

__device__ __forceinline__ float fexp2(float x) {
#if __has_builtin(__builtin_amdgcn_exp2f)
    return __builtin_amdgcn_exp2f(x);
#else
    return exp2f(x);
#endif
}
__device__ __forceinline__ float frcp(float x) {
#if __has_builtin(__builtin_amdgcn_rcpf)
    return __builtin_amdgcn_rcpf(x);
#else
    return 1.0f / x;
#endif
}
__device__ __forceinline__ float fsigmoid(float x) {
    return frcp(1.0f + fexp2(-LOG2E * x));
}
__device__ __forceinline__ float ftanh2(float x) {
    return __builtin_fmaf(2.0f, frcp(1.0f + fexp2(-2.0f * LOG2E * x)), -1.0f);
}
__device__ __forceinline__ void ssleep_s() {      // scanner: wake fast
#if __has_builtin(__builtin_amdgcn_s_sleep)
    __builtin_amdgcn_s_sleep(4);
#endif
}
__device__ __forceinline__ void ssleep_p() {      // producer: low poll traffic
#if __has_builtin(__builtin_amdgcn_s_sleep)
    __builtin_amdgcn_s_sleep(32);
#endif
}
__device__ __forceinline__ void sbar0() {
#if __has_builtin(__builtin_amdgcn_sched_barrier)
    __builtin_amdgcn_sched_barrier(0);
#endif
}

// ---------------------------------------------------------------------------
// prep: W_ih -> frag-linear RNE bf16 g_Wf[ks][ct][lane][8] (2-term split).
// ---------------------------------------------------------------------------
__global__ void prep_w(const float* __restrict__ W) {
    int f = blockIdx.x * 256 + threadIdx.x;
    if (f >= KSTEPS * NCT * 64) return;
    const int l  = f & 63;
    const int ct = (f >> 6) % NCT;
    const int ks = (f >> 6) / NCT;
    const int n  = ct * 16 + (l & 15);
    const int k0 = ks * 32 + (l >> 4) * 8;
    ushort v[8] __attribute__((aligned(16)));
#pragma unroll
    for (int j = 0; j < 8; ++j) v[j] = 0;
    if (n < G4) {
        const float* wp = &W[(size_t)n * D_IN + k0];
#pragma unroll
        for (int j = 0; j < 8; ++j) {
            unsigned u = __float_as_uint(wp[j]);
            v[j] = (ushort)((u + 0x7FFFu + ((u >> 16) & 1u)) >> 16);  // RNE bf16
        }
    }
    *(uint4*)&g_Wf[(size_t)f * 8] = *(const uint4*)v;
}

__device__ __forceinline__ void pack2(float f0, float f1, unsigned& h, unsigned& l) {
    unsigned u0 = __float_as_uint(f0), u1 = __float_as_uint(f1);
    h = (u0 >> 16) | (u1 & 0xffff0000u);
    float d0 = f0 - __uint_as_float(u0 & 0xffff0000u);
    float d1 = f1 - __uint_as_float(u1 & 0xffff0000u);
    l = (__float_as_uint(d0) >> 16) | (__float_as_uint(d1) & 0xffff0000u);
}

#define REP25(M) M(0) M(1) M(2) M(3) M(4) M(5) M(6) M(7) M(8) M(9) \
                 M(10) M(11) M(12) M(13) M(14) M(15) M(16) M(17) M(18) M(19) \
                 M(20) M(21) M(22) M(23) M(24)

__device__ __forceinline__ unsigned pk2f16(float a, float b) {
#if __has_builtin(__builtin_amdgcn_cvt_pkrtz)
    return __builtin_bit_cast(unsigned, __builtin_amdgcn_cvt_pkrtz(a, b));
#else
    f16x2 v = {(_Float16)a, (_Float16)b};
    return __builtin_bit_cast(unsigned, v);
#endif
}

#if __has_builtin(__builtin_amdgcn_fdot2)
#define FD(hu_, wu_, cc_) __builtin_amdgcn_fdot2( \
    __builtin_bit_cast(f16x2, (hu_)), __builtin_bit_cast(f16x2, (wu_)), (cc_), false)
#else
#define FD(hu_, wu_, cc_) ((cc_) \
    + (float)__builtin_bit_cast(f16x2, (hu_))[0] * (float)__builtin_bit_cast(f16x2, (wu_))[0] \
    + (float)__builtin_bit_cast(f16x2, (hu_))[1] * (float)__builtin_bit_cast(f16x2, (wu_))[1])
#endif

// ---------------------------------------------------------------------------
// FUSED (R18 + residence fixes): producers get CONTIGUOUS chunk ranges so
// early waves exit in ~12 us (strided kept all 7 alive polling the whole
// scan); ring 5 slots; producer poll sleep 4x longer. Scanner unchanged.
// ---------------------------------------------------------------------------
__global__ __launch_bounds__(512, 1) void lstm_fused(
    const float* __restrict__ x, const int* __restrict__ mask,
    const float* __restrict__ b_ih, const float* __restrict__ b_hh,
    const float* __restrict__ W_hh, const float* __restrict__ W_cls,
    const float* __restrict__ b_cls, float* __restrict__ out)
{
    __shared__ float ldsxg[NSLOT * CHROWS * ROWSTR];   // 133,120 B
    __shared__ int   s_flag[17];                       // [0..15]=ready, [16]=done_upto

    const int b    = blockIdx.x;
    const int tid  = threadIdx.x;
    const int wv   = tid >> 6;
    const int lane = tid & 63;

    int s = 0;
#pragma unroll
    for (int k = 0; k < 8; ++k) s += mask[b * S_LEN + lane + 64 * k];
#pragma unroll
    for (int off = 1; off < 64; off <<= 1) s += __shfl_xor(s, off, 64);
    const int len = s;                               // >= 1
    const int NCc = (len + CHROWS - 1) >> 5;         // live chunks

    if (tid < 17) s_flag[tid] = 0;
    __syncthreads();                                 // the ONLY block barrier

    volatile int* vflag = s_flag;

    if (wv != 0) {
        // ---- producers (waves 1..7): contiguous ranges, fast B, exit ----
        __builtin_amdgcn_s_setprio(0);
        const int c0w = ((wv - 1) * NCc) / 7;        // contiguous assignment
        const int c1w = (wv * NCc) / 7;
        const int lr  = lane & 15;
        const int kch = (lane >> 4) * 8;
        for (int c = c0w; c < c1w; ++c) {
            const int r0 = c * CHROWS;
            const float* xr0 = x + ((size_t)b * S_LEN + r0 + lr) * D_IN;
            const float* xr1 = xr0 + (size_t)16 * D_IN;

            f32x4 acc0[NCT], acc1[NCT];
#pragma unroll
            for (int i = 0; i < NCT; ++i) {
                acc0[i] = (f32x4){0.f, 0.f, 0.f, 0.f};
                acc1[i] = (f32x4){0.f, 0.f, 0.f, 0.f};
            }
            float4 ac0 = *(const float4*)(xr0 + kch);
            float4 ac1 = *(const float4*)(xr0 + kch + 4);
            float4 ac2 = *(const float4*)(xr1 + kch);
            float4 ac3 = *(const float4*)(xr1 + kch + 4);
            float4 an0, an1, an2, an3;

            s16x8 Bc[NCT];                           // register-resident B(ks)
            {
                const ushort* bp0 = g_Wf + (size_t)lane * 8;
#pragma unroll
                for (int ct = 0; ct < NCT; ++ct)
                    Bc[ct] = *(const s16x8*)(bp0 + ct * 512);
            }

            for (int ks = 0; ks < KSTEPS; ++ks) {
                if (ks < KSTEPS - 1) {               // A prefetch (HBM)
                    const int k1 = (ks + 1) * 32 + kch;
                    an0 = *(const float4*)(xr0 + k1);
                    an1 = *(const float4*)(xr0 + k1 + 4);
                    an2 = *(const float4*)(xr1 + k1);
                    an3 = *(const float4*)(xr1 + k1 + 4);
                }
                uint4 h0, l0, h1, l1;
                pack2(ac0.x, ac0.y, h0.x, l0.x); pack2(ac0.z, ac0.w, h0.y, l0.y);
                pack2(ac1.x, ac1.y, h0.z, l0.z); pack2(ac1.z, ac1.w, h0.w, l0.w);
                pack2(ac2.x, ac2.y, h1.x, l1.x); pack2(ac2.z, ac2.w, h1.y, l1.y);
                pack2(ac3.x, ac3.y, h1.z, l1.z); pack2(ac3.z, ac3.w, h1.w, l1.w);
                s16x8 A0h = *(s16x8*)&h0, A0l = *(s16x8*)&l0;
                s16x8 A1h = *(s16x8*)&h1, A1l = *(s16x8*)&l1;
#pragma unroll
                for (int ct = 0; ct < NCT; ++ct) {
                    acc0[ct] = __builtin_amdgcn_mfma_f32_16x16x32_bf16(A0h, Bc[ct], acc0[ct], 0, 0, 0);
                    acc0[ct] = __builtin_amdgcn_mfma_f32_16x16x32_bf16(A0l, Bc[ct], acc0[ct], 0, 0, 0);
                    acc1[ct] = __builtin_amdgcn_mfma_f32_16x16x32_bf16(A1h, Bc[ct], acc1[ct], 0, 0, 0);
                    acc1[ct] = __builtin_amdgcn_mfma_f32_16x16x32_bf16(A1l, Bc[ct], acc1[ct], 0, 0, 0);
                }
                if (ks < KSTEPS - 1) {               // B(ks+1) load-after-use
                    const ushort* bp = g_Wf + (size_t)(ks + 1) * FR_KS + (size_t)lane * 8;
#pragma unroll
                    for (int ct = 0; ct < NCT; ++ct)
                        Bc[ct] = *(const s16x8*)(bp + ct * 512);
                }
                ac0 = an0; ac1 = an1; ac2 = an2; ac3 = an3;
            }

            // back-pressure: slot free once scanner finished chunk c-(NSLOT-1)
            if (c >= NSLOT) {
                while (vflag[16] < c - (NSLOT - 1)) ssleep_p();
            }
            float* slot = ldsxg + (size_t)(c % NSLOT) * (CHROWS * ROWSTR);
            const int orow = (lane >> 4) * 4;
#pragma unroll
            for (int ct = 0; ct < NCT; ++ct) {
                const int n = ct * 16 + (lane & 15);
                if (n < G4) {
                    const int g = n / 50, j = n - g * 50;
                    const int off = j * 4 + g;       // [j][gate]
                    const float bias = b_ih[n] + b_hh[n];
#pragma unroll
                    for (int e = 0; e < 4; ++e) {
                        slot[(orow + e) * ROWSTR + off]      = acc0[ct][e] + bias;
                        slot[(orow + 16 + e) * ROWSTR + off] = acc1[ct][e] + bias;
                    }
                }
            }
            asm volatile("s_waitcnt lgkmcnt(0)" ::: "memory");  // data before flag
            if (lane == 0) vflag[c] = 1;
        }
        return;                                      // producers exit early
    }

    // ---------------- scanner (wave 0), high priority ----------------
    __builtin_amdgcn_s_setprio(1);
    const bool act = (lane < H_DIM);
    const int  l   = lane;
    const int  ll  = act ? lane : 0;
    const float* wr0 = W_hh + (size_t)ll * H_DIM;
    const float* wr1 = W_hh + (size_t)(50 + ll) * H_DIM;
    const float* wr2 = W_hh + (size_t)(100 + ll) * H_DIM;
    const float* wr3 = W_hh + (size_t)(150 + ll) * H_DIM;

#define WDECL(q) unsigned wi_##q, wf_##q, wg_##q, wo_##q;
    REP25(WDECL)
#undef WDECL
#define WLOAD(q) \
    wi_##q = pk2f16(wr0[2*q], wr0[2*q+1]); \
    wf_##q = pk2f16(wr1[2*q], wr1[2*q+1]); \
    wg_##q = pk2f16(wr2[2*q], wr2[2*q+1]); \
    wo_##q = pk2f16(wr3[2*q], wr3[2*q+1]);
    REP25(WLOAD)
#undef WLOAD
#define WPIN(q) asm volatile("" : "+v"(wi_##q), "+v"(wf_##q), "+v"(wg_##q), "+v"(wo_##q));
    REP25(WPIN)
#undef WPIN

    float h = 0.f, c = 0.f;

    auto step = [&](float4& v, const float* slot, int nextrow) {
#if __has_builtin(__builtin_amdgcn_mov_dpp)
        int hsw = __builtin_amdgcn_mov_dpp(__float_as_int(h), 0xB1, 0xF, 0xF, true);
#else
        int hsw = __float_as_int(__shfl_xor(h, 1, 64));
#endif
        unsigned hu = pk2f16(h, __int_as_float(hsw));

        float ai0 = v.x, af0 = v.y, aq0 = v.z, ao0 = v.w;
        float ai1 = 0.f, af1 = 0.f, aq1 = 0.f, ao1 = 0.f;

#define RDECL(q) unsigned r_##q = (unsigned)__builtin_amdgcn_readlane((int)hu, 2*q);
        REP25(RDECL)
#undef RDECL
#define DOTA(q) { ai0 = FD(r_##q, wi_##q, ai0); af0 = FD(r_##q, wf_##q, af0); \
                  aq0 = FD(r_##q, wg_##q, aq0); ao0 = FD(r_##q, wo_##q, ao0); }
#define DOTB(q) { ai1 = FD(r_##q, wi_##q, ai1); af1 = FD(r_##q, wf_##q, af1); \
                  aq1 = FD(r_##q, wg_##q, aq1); ao1 = FD(r_##q, wo_##q, ao1); }
        DOTA(0)  DOTB(1)  DOTA(2)  DOTB(3)  DOTA(4)
        DOTB(5)  DOTA(6)  DOTB(7)  DOTA(8)  DOTB(9)
        DOTA(10) DOTB(11) DOTA(12) DOTB(13) DOTA(14)
        DOTB(15) DOTA(16) DOTB(17) DOTA(18) DOTB(19)
        DOTA(20) DOTB(21) DOTA(22) DOTB(23) DOTA(24)
#undef DOTA
#undef DOTB
        float ai = ai0 + ai1, af = af0 + af1;
        float aq = aq0 + aq1, ao = ao0 + ao1;

        sbar0();
        v = *(const float4*)(slot + nextrow * ROWSTR + ll * 4);  // ds_read_b128
        sbar0();

        float ig = fsigmoid(ai), fg = fsigmoid(af);
        float gg = ftanh2(aq),   og = fsigmoid(ao);
        c = fg * c + ig * gg;
        h = og * ftanh2(c);
    };

    for (int cc = 0; cc < NCc; ++cc) {
        while (vflag[cc] == 0) ssleep_s();           // wait for chunk
        const float* slot = ldsxg + (size_t)(cc % NSLOT) * (CHROWS * ROWSTR);
        const int n = (cc == NCc - 1) ? (len - cc * CHROWS) : CHROWS;

        float4 vA = *(const float4*)(slot + 0 * ROWSTR + ll * 4);
        float4 vB = *(const float4*)(slot + (n > 1 ? 1 : 0) * ROWSTR + ll * 4);

        int tl = 0;
        while (tl < n) {
            { int nr = tl + 2 < n ? tl + 2 : n - 1; step(vA, slot, nr); }
            ++tl; if (tl >= n) break;
            { int nr = tl + 2 < n ? tl + 2 : n - 1; step(vB, slot, nr); }
            ++tl;
        }
        if (lane == 0) vflag[16] = cc + 1;           // release slot
    }

    float p0 = act ? h * W_cls[l]          : 0.f;
    float p1 = act ? h * W_cls[H_DIM + l]  : 0.f;
#pragma unroll
    for (int off = 1; off < 64; off <<= 1) {
        p0 += __shfl_xor(p0, off, 64);
        p1 += __shfl_xor(p1, off, 64);
    }
    if (lane == 0) {
        out[2 * b]     = p0 + b_cls[0];
        out[2 * b + 1] = p1 + b_cls[1];
    }
}

extern "C" void kernel_launch(void* const* d_in, const int* in_sizes, int n_in,
                              void* d_out, int out_size, void* d_ws, size_t ws_size,
                              hipStream_t stream) {
    const float* x     = (const float*)d_in[0];
    const int*   mask  = (const int*)  d_in[1];
    const float* W_ih  = (const float*)d_in[2];
    const float* W_hh  = (const float*)d_in[3];
    const float* b_ih  = (const float*)d_in[4];
    const float* b_hh  = (const float*)d_in[5];
    const float* W_cls = (const float*)d_in[6];
    const float* b_cls = (const float*)d_in[7];
    float* out = (float*)d_out;

    hipLaunchKernelGGL(prep_w, dim3(78), dim3(256), 0, stream, W_ih);
    hipLaunchKernelGGL(lstm_fused, dim3(256), dim3(512), 0, stream,
                       x, mask, b_ih, b_hh, W_hh, W_cls, b_cls, out);
}

// Round 20
// 231.267 us; speedup vs baseline: 1.1914x; 1.1914x over previous
//
#include <hip/hip_runtime.h>
#include <math.h>

#define S_LEN 512
#define D_IN  768
#define H_DIM 50
#define G4    200
#define NCT   13
#define KSTEPS 24        // 768/32
#define FR_KS  6656      // ushorts per K-step: 13 ct x 64 lanes x 8
#define CHROWS 32        // rows per chunk
#define NSLOT  4         // LDS ring slots
#define ROWSTR 208       // floats per LDS row

typedef float   f32x4 __attribute__((ext_vector_type(4)));
typedef short   s16x8 __attribute__((ext_vector_type(8)));
typedef _Float16 f16x2 __attribute__((ext_vector_type(2)));

__device__ ushort g_Wf[KSTEPS * FR_KS];   // [ks][ct][lane][8], RNE bf16

#define LOG2E 1.44269504f

__device__ __forceinline__ float fexp2(float x) {
#if __has_builtin(__builtin_amdgcn_exp2f)
    return __builtin_amdgcn_exp2f(x);
#else
    return exp2f(x);
#endif
}
__device__ __forceinline__ float frcp(float x) {
#if __has_builtin(__builtin_amdgcn_rcpf)
    return __builtin_amdgcn_rcpf(x);
#else
    return 1.0f / x;
#endif
}
__device__ __forceinline__ float fsigmoid(float x) {
    return frcp(1.0f + fexp2(-LOG2E * x));
}
__device__ __forceinline__ float ftanh2(float x) {
    return __builtin_fmaf(2.0f, frcp(1.0f + fexp2(-2.0f * LOG2E * x)), -1.0f);
}
__device__ __forceinline__ void ssleep() {
#if __has_builtin(__builtin_amdgcn_s_sleep)
    __builtin_amdgcn_s_sleep(8);
#endif
}
__device__ __forceinline__ void sbar0() {
#if __has_builtin(__builtin_amdgcn_sched_barrier)
    __builtin_amdgcn_sched_barrier(0);
#endif
}

// ---------------------------------------------------------------------------
// prep: W_ih -> frag-linear RNE bf16 g_Wf[ks][ct][lane][8] (2-term split).
// ---------------------------------------------------------------------------
__global__ void prep_w(const float* __restrict__ W) {
    int f = blockIdx.x * 256 + threadIdx.x;
    if (f >= KSTEPS * NCT * 64) return;
    const int l  = f & 63;
    const int ct = (f >> 6) % NCT;
    const int ks = (f >> 6) / NCT;
    const int n  = ct * 16 + (l & 15);
    const int k0 = ks * 32 + (l >> 4) * 8;
    ushort v[8] __attribute__((aligned(16)));
#pragma unroll
    for (int j = 0; j < 8; ++j) v[j] = 0;
    if (n < G4) {
        const float* wp = &W[(size_t)n * D_IN + k0];
#pragma unroll
        for (int j = 0; j < 8; ++j) {
            unsigned u = __float_as_uint(wp[j]);
            v[j] = (ushort)((u + 0x7FFFu + ((u >> 16) & 1u)) >> 16);  // RNE bf16
        }
    }
    *(uint4*)&g_Wf[(size_t)f * 8] = *(const uint4*)v;
}

__device__ __forceinline__ void pack2(float f0, float f1, unsigned& h, unsigned& l) {
    unsigned u0 = __float_as_uint(f0), u1 = __float_as_uint(f1);
    h = (u0 >> 16) | (u1 & 0xffff0000u);
    float d0 = f0 - __uint_as_float(u0 & 0xffff0000u);
    float d1 = f1 - __uint_as_float(u1 & 0xffff0000u);
    l = (__float_as_uint(d0) >> 16) | (__float_as_uint(d1) & 0xffff0000u);
}

#define REP25(M) M(0) M(1) M(2) M(3) M(4) M(5) M(6) M(7) M(8) M(9) \
                 M(10) M(11) M(12) M(13) M(14) M(15) M(16) M(17) M(18) M(19) \
                 M(20) M(21) M(22) M(23) M(24)

__device__ __forceinline__ unsigned pk2f16(float a, float b) {
#if __has_builtin(__builtin_amdgcn_cvt_pkrtz)
    return __builtin_bit_cast(unsigned, __builtin_amdgcn_cvt_pkrtz(a, b));
#else
    f16x2 v = {(_Float16)a, (_Float16)b};
    return __builtin_bit_cast(unsigned, v);
#endif
}

#if __has_builtin(__builtin_amdgcn_fdot2)
#define FD(hu_, wu_, cc_) __builtin_amdgcn_fdot2( \
    __builtin_bit_cast(f16x2, (hu_)), __builtin_bit_cast(f16x2, (wu_)), (cc_), false)
#else
#define FD(hu_, wu_, cc_) ((cc_) \
    + (float)__builtin_bit_cast(f16x2, (hu_))[0] * (float)__builtin_bit_cast(f16x2, (wu_))[0] \
    + (float)__builtin_bit_cast(f16x2, (hu_))[1] * (float)__builtin_bit_cast(f16x2, (wu_))[1])
#endif

// ---------------------------------------------------------------------------
// FUSED (R18 exact): ring + FAST producers + early exit + setprio. Producers
// (waves 1-7, prio 0) compute chunks with register-prefetched B (~4 us/chunk,
// strided assignment so chunks 0-6 appear in parallel), write into a 4-slot
// LDS ring, sleep on back-pressure, exit when done. Scanner (wave 0, prio 1)
// reads rows via ds_read_b128. Measured 231.3 us total.
// ---------------------------------------------------------------------------
__global__ __launch_bounds__(512, 1) void lstm_fused(
    const float* __restrict__ x, const int* __restrict__ mask,
    const float* __restrict__ b_ih, const float* __restrict__ b_hh,
    const float* __restrict__ W_hh, const float* __restrict__ W_cls,
    const float* __restrict__ b_cls, float* __restrict__ out)
{
    __shared__ float ldsxg[NSLOT * CHROWS * ROWSTR];   // 106,496 B
    __shared__ int   s_flag[17];                       // [0..15]=ready, [16]=done_upto

    const int b    = blockIdx.x;
    const int tid  = threadIdx.x;
    const int wv   = tid >> 6;
    const int lane = tid & 63;

    int s = 0;
#pragma unroll
    for (int k = 0; k < 8; ++k) s += mask[b * S_LEN + lane + 64 * k];
#pragma unroll
    for (int off = 1; off < 64; off <<= 1) s += __shfl_xor(s, off, 64);
    const int len = s;                               // >= 1
    const int NCc = (len + CHROWS - 1) >> 5;         // live chunks

    if (tid < 17) s_flag[tid] = 0;
    __syncthreads();                                 // the ONLY block barrier

    volatile int* vflag = s_flag;

    if (wv != 0) {
        // ---- producers (waves 1..7): fast B-reg prefetch, ring, exit ----
        __builtin_amdgcn_s_setprio(0);
        const int lr  = lane & 15;
        const int kch = (lane >> 4) * 8;
        for (int c = wv - 1; c < NCc; c += 7) {
            const int r0 = c * CHROWS;
            const float* xr0 = x + ((size_t)b * S_LEN + r0 + lr) * D_IN;
            const float* xr1 = xr0 + (size_t)16 * D_IN;

            f32x4 acc0[NCT], acc1[NCT];
#pragma unroll
            for (int i = 0; i < NCT; ++i) {
                acc0[i] = (f32x4){0.f, 0.f, 0.f, 0.f};
                acc1[i] = (f32x4){0.f, 0.f, 0.f, 0.f};
            }
            float4 ac0 = *(const float4*)(xr0 + kch);
            float4 ac1 = *(const float4*)(xr0 + kch + 4);
            float4 ac2 = *(const float4*)(xr1 + kch);
            float4 ac3 = *(const float4*)(xr1 + kch + 4);
            float4 an0, an1, an2, an3;

            s16x8 Bc[NCT];                           // register-resident B(ks)
            {
                const ushort* bp0 = g_Wf + (size_t)lane * 8;
#pragma unroll
                for (int ct = 0; ct < NCT; ++ct)
                    Bc[ct] = *(const s16x8*)(bp0 + ct * 512);
            }

            for (int ks = 0; ks < KSTEPS; ++ks) {
                if (ks < KSTEPS - 1) {               // A prefetch (HBM)
                    const int k1 = (ks + 1) * 32 + kch;
                    an0 = *(const float4*)(xr0 + k1);
                    an1 = *(const float4*)(xr0 + k1 + 4);
                    an2 = *(const float4*)(xr1 + k1);
                    an3 = *(const float4*)(xr1 + k1 + 4);
                }
                uint4 h0, l0, h1, l1;
                pack2(ac0.x, ac0.y, h0.x, l0.x); pack2(ac0.z, ac0.w, h0.y, l0.y);
                pack2(ac1.x, ac1.y, h0.z, l0.z); pack2(ac1.z, ac1.w, h0.w, l0.w);
                pack2(ac2.x, ac2.y, h1.x, l1.x); pack2(ac2.z, ac2.w, h1.y, l1.y);
                pack2(ac3.x, ac3.y, h1.z, l1.z); pack2(ac3.z, ac3.w, h1.w, l1.w);
                s16x8 A0h = *(s16x8*)&h0, A0l = *(s16x8*)&l0;
                s16x8 A1h = *(s16x8*)&h1, A1l = *(s16x8*)&l1;
#pragma unroll
                for (int ct = 0; ct < NCT; ++ct) {
                    acc0[ct] = __builtin_amdgcn_mfma_f32_16x16x32_bf16(A0h, Bc[ct], acc0[ct], 0, 0, 0);
                    acc0[ct] = __builtin_amdgcn_mfma_f32_16x16x32_bf16(A0l, Bc[ct], acc0[ct], 0, 0, 0);
                    acc1[ct] = __builtin_amdgcn_mfma_f32_16x16x32_bf16(A1h, Bc[ct], acc1[ct], 0, 0, 0);
                    acc1[ct] = __builtin_amdgcn_mfma_f32_16x16x32_bf16(A1l, Bc[ct], acc1[ct], 0, 0, 0);
                }
                if (ks < KSTEPS - 1) {               // B(ks+1) load-after-use
                    const ushort* bp = g_Wf + (size_t)(ks + 1) * FR_KS + (size_t)lane * 8;
#pragma unroll
                    for (int ct = 0; ct < NCT; ++ct)
                        Bc[ct] = *(const s16x8*)(bp + ct * 512);
                }
                ac0 = an0; ac1 = an1; ac2 = an2; ac3 = an3;
            }

            // back-pressure: slot free once scanner finished chunk c-4
            if (c >= NSLOT) {
                while (vflag[16] < c - (NSLOT - 1)) ssleep();
            }
            float* slot = ldsxg + (size_t)(c & (NSLOT - 1)) * (CHROWS * ROWSTR);
            const int orow = (lane >> 4) * 4;
#pragma unroll
            for (int ct = 0; ct < NCT; ++ct) {
                const int n = ct * 16 + (lane & 15);
                if (n < G4) {
                    const int g = n / 50, j = n - g * 50;
                    const int off = j * 4 + g;       // [j][gate]
                    const float bias = b_ih[n] + b_hh[n];
#pragma unroll
                    for (int e = 0; e < 4; ++e) {
                        slot[(orow + e) * ROWSTR + off]      = acc0[ct][e] + bias;
                        slot[(orow + 16 + e) * ROWSTR + off] = acc1[ct][e] + bias;
                    }
                }
            }
            asm volatile("s_waitcnt lgkmcnt(0)" ::: "memory");  // data before flag
            if (lane == 0) vflag[c] = 1;
        }
        return;                                      // producers exit early
    }

    // ---------------- scanner (wave 0), high priority ----------------
    __builtin_amdgcn_s_setprio(1);
    const bool act = (lane < H_DIM);
    const int  l   = lane;
    const int  ll  = act ? lane : 0;
    const float* wr0 = W_hh + (size_t)ll * H_DIM;
    const float* wr1 = W_hh + (size_t)(50 + ll) * H_DIM;
    const float* wr2 = W_hh + (size_t)(100 + ll) * H_DIM;
    const float* wr3 = W_hh + (size_t)(150 + ll) * H_DIM;

#define WDECL(q) unsigned wi_##q, wf_##q, wg_##q, wo_##q;
    REP25(WDECL)
#undef WDECL
#define WLOAD(q) \
    wi_##q = pk2f16(wr0[2*q], wr0[2*q+1]); \
    wf_##q = pk2f16(wr1[2*q], wr1[2*q+1]); \
    wg_##q = pk2f16(wr2[2*q], wr2[2*q+1]); \
    wo_##q = pk2f16(wr3[2*q], wr3[2*q+1]);
    REP25(WLOAD)
#undef WLOAD
#define WPIN(q) asm volatile("" : "+v"(wi_##q), "+v"(wf_##q), "+v"(wg_##q), "+v"(wo_##q));
    REP25(WPIN)
#undef WPIN

    float h = 0.f, c = 0.f;

    auto step = [&](float4& v, const float* slot, int nextrow) {
#if __has_builtin(__builtin_amdgcn_mov_dpp)
        int hsw = __builtin_amdgcn_mov_dpp(__float_as_int(h), 0xB1, 0xF, 0xF, true);
#else
        int hsw = __float_as_int(__shfl_xor(h, 1, 64));
#endif
        unsigned hu = pk2f16(h, __int_as_float(hsw));

        float ai0 = v.x, af0 = v.y, aq0 = v.z, ao0 = v.w;
        float ai1 = 0.f, af1 = 0.f, aq1 = 0.f, ao1 = 0.f;

#define RDECL(q) unsigned r_##q = (unsigned)__builtin_amdgcn_readlane((int)hu, 2*q);
        REP25(RDECL)
#undef RDECL
#define DOTA(q) { ai0 = FD(r_##q, wi_##q, ai0); af0 = FD(r_##q, wf_##q, af0); \
                  aq0 = FD(r_##q, wg_##q, aq0); ao0 = FD(r_##q, wo_##q, ao0); }
#define DOTB(q) { ai1 = FD(r_##q, wi_##q, ai1); af1 = FD(r_##q, wf_##q, af1); \
                  aq1 = FD(r_##q, wg_##q, aq1); ao1 = FD(r_##q, wo_##q, ao1); }
        DOTA(0)  DOTB(1)  DOTA(2)  DOTB(3)  DOTA(4)
        DOTB(5)  DOTA(6)  DOTB(7)  DOTA(8)  DOTB(9)
        DOTA(10) DOTB(11) DOTA(12) DOTB(13) DOTA(14)
        DOTB(15) DOTA(16) DOTB(17) DOTA(18) DOTB(19)
        DOTA(20) DOTB(21) DOTA(22) DOTB(23) DOTA(24)
#undef DOTA
#undef DOTB
        float ai = ai0 + ai1, af = af0 + af1;
        float aq = aq0 + aq1, ao = ao0 + ao1;

        sbar0();
        v = *(const float4*)(slot + nextrow * ROWSTR + ll * 4);  // ds_read_b128
        sbar0();

        float ig = fsigmoid(ai), fg = fsigmoid(af);
        float gg = ftanh2(aq),   og = fsigmoid(ao);
        c = fg * c + ig * gg;
        h = og * ftanh2(c);
    };

    for (int cc = 0; cc < NCc; ++cc) {
        while (vflag[cc] == 0) ssleep();             // wait for chunk
        const float* slot = ldsxg + (size_t)(cc & (NSLOT - 1)) * (CHROWS * ROWSTR);
        const int n = (cc == NCc - 1) ? (len - cc * CHROWS) : CHROWS;

        float4 vA = *(const float4*)(slot + 0 * ROWSTR + ll * 4);
        float4 vB = *(const float4*)(slot + (n > 1 ? 1 : 0) * ROWSTR + ll * 4);

        int tl = 0;
        while (tl < n) {
            { int nr = tl + 2 < n ? tl + 2 : n - 1; step(vA, slot, nr); }
            ++tl; if (tl >= n) break;
            { int nr = tl + 2 < n ? tl + 2 : n - 1; step(vB, slot, nr); }
            ++tl;
        }
        if (lane == 0) vflag[16] = cc + 1;           // release slot
    }

    float p0 = act ? h * W_cls[l]          : 0.f;
    float p1 = act ? h * W_cls[H_DIM + l]  : 0.f;
#pragma unroll
    for (int off = 1; off < 64; off <<= 1) {
        p0 += __shfl_xor(p0, off, 64);
        p1 += __shfl_xor(p1, off, 64);
    }
    if (lane == 0) {
        out[2 * b]     = p0 + b_cls[0];
        out[2 * b + 1] = p1 + b_cls[1];
    }
}

extern "C" void kernel_launch(void* const* d_in, const int* in_sizes, int n_in,
                              void* d_out, int out_size, void* d_ws, size_t ws_size,
                              hipStream_t stream) {
    const float* x     = (const float*)d_in[0];
    const int*   mask  = (const int*)  d_in[1];
    const float* W_ih  = (const float*)d_in[2];
    const float* W_hh  = (const float*)d_in[3];
    const float* b_ih  = (const float*)d_in[4];
    const float* b_hh  = (const float*)d_in[5];
    const float* W_cls = (const float*)d_in[6];
    const float* b_cls = (const float*)d_in[7];
    float* out = (float*)d_out;

    hipLaunchKernelGGL(prep_w, dim3(78), dim3(256), 0, stream, W_ih);
    hipLaunchKernelGGL(lstm_fused, dim3(256), dim3(512), 0, stream,
                       x, mask, b_ih, b_hh, W_hh, W_cls, b_cls, out);
}